// Round 12
// baseline (355.011 us; speedup 1.0000x reference)
//
#include <hip/hip_runtime.h>
#include <hip/hip_bf16.h>

#define TS 20
#define DNUM 128
#define NWORDS 16384
#define NBLK 256                    // 1 block/CU; bid>>7 = dir

typedef __attribute__((ext_vector_type(8))) short s8v;
typedef __attribute__((ext_vector_type(4))) float f4v;

#define L2E 1.4426950408889634f

__device__ __forceinline__ unsigned short bf16_rne(float f) {
  union { float f; unsigned u; } x; x.f = f;
  unsigned r = x.u + 0x7fffu + ((x.u >> 16) & 1u);
  return (unsigned short)(r >> 16);
}

// tab4[dir][c][u] = float4(-L2E*(xz+b_rec_z), -L2E*(xr+b_rec_r), 2*L2E*xh, unused)
__global__ void build_tab(const float* __restrict__ emb,
                          const float* __restrict__ wkF, const float* __restrict__ bF,
                          const float* __restrict__ wkB, const float* __restrict__ bB,
                          float* __restrict__ tab4) {
  int gid = blockIdx.x * 256 + threadIdx.x;
  if (gid >= 2 * 129 * 768) return;
  int dir = gid / (129 * 768);
  int rem = gid - dir * (129 * 768);
  int c = rem / 768, j = rem - (rem / 768) * 768;
  int g = j >> 8, u = j & 255;
  const float* Wk = dir ? wkB : wkF;
  const float* bb = dir ? bB : bF;
  float s = bb[j];                       // b[0] row = input bias
  const float* er = emb + c * DNUM;
  #pragma unroll 4
  for (int d = 0; d < DNUM; ++d) s = fmaf(er[d], Wk[d * 768 + j], s);
  float v = (g < 2) ? (-L2E * (s + bb[768 + j])) : (2.f * L2E * s);
  tab4[((((size_t)dir * 129 + c) * 256 + u) * 4) + g] = v;
}

// Pack Wr into bf16 MFMA-B-fragment order (verified r1), pre-scaled per gate.
__global__ void pack_wr(const float* __restrict__ wrF, const float* __restrict__ wrB,
                        uint4* __restrict__ wp) {
  int gid = blockIdx.x * 256 + threadIdx.x;
  if (gid >= 2 * 48 * 8 * 64) return;
  int dir = gid / (48 * 8 * 64);
  int rem = gid - dir * (48 * 8 * 64);
  int ct = rem / (8 * 64);
  int kk = (rem / 64) & 7;
  int lane = rem & 63;
  const float* Wr = dir ? wrB : wrF;
  int n = ct * 16 + (lane & 15);
  int k0 = kk * 32 + (lane >> 4) * 8;
  const float sc = (ct >> 4) == 2 ? (2.f * L2E) : (-L2E);
  union { unsigned short v[8]; uint4 q; } u;
  #pragma unroll
  for (int e = 0; e < 8; ++e) u.v[e] = bf16_rne(sc * Wr[(k0 + e) * 768 + n]);
  wp[gid] = u.q;
}

// 256 blocks (1/CU) x 512 threads (8 waves). Fused 32-word step (both
// 16-word groups in one barrier pair; one bh LDS read feeds A and B MFMAs):
//   [cc reads; fused kk-loop] b1 [gA+gB gathers issued; epi-A; epi-B] b2
// All table gathers AFTER b1 so no float4 regs are live across the
// weight-heavy MFMA phase (r11's spill cause). 256 b128 + 2 barriers per
// 32 words (r8: 384 + 4).
__global__ __launch_bounds__(512, 1) void gru_main(
    const int* __restrict__ chars, const float* __restrict__ tab4,
    const uint4* __restrict__ wrp, const float* __restrict__ bf_,
    const float* __restrict__ bb_, float* __restrict__ out) {
  const int bid = blockIdx.x;
  const int dir = bid >> 7;            // 128 blocks per direction
  const int wslot = bid & 127;
  const float4* T4 = (const float4*)tab4 + (size_t)dir * 129 * 256;
  const uint4* WP = wrp + dir * (48 * 8 * 64);
  const float* brec = (dir ? bb_ : bf_) + 768;   // b[1] = recurrent bias

  const int tid = threadIdx.x;
  const int w = tid >> 6, lane = tid & 63;
  const int lr = lane >> 4, lc = lane & 15;
  const int u0 = w * 32 + lc, u1 = u0 + 16;      // wave's two unit-tiles

  __shared__ uint4 bhl[8192];                    // 128KB h-gate weights
  __shared__ unsigned short hbf[32][264];        // 16.9KB; A rows 0-15, B 16-31
  __shared__ int sch[32 * TS];                   // 2.56KB chars

  for (int i = tid; i < 8192; i += 512) bhl[i] = WP[16384 + i];

  // z,r weights resident: 2 ct x 8 kk x 2 gates = 32 uint4 = 128 regs
  // (compiler parks most in AGPRs; B-operands tolerate that — r8 evidence).
  uint4 Wz[2][8], Wrr[2][8];
  #pragma unroll
  for (int ct = 0; ct < 2; ++ct)
    #pragma unroll
    for (int kk = 0; kk < 8; ++kk) {
      Wz[ct][kk]  = WP[((w * 2 + ct) * 8 + kk) * 64 + lane];
      Wrr[ct][kk] = WP[((16 + w * 2 + ct) * 8 + kk) * 64 + lane];
    }

  float brh[2];
  brh[0] = 2.f * L2E * brec[512 + u0];
  brh[1] = 2.f * L2E * brec[512 + u1];

  #pragma unroll 1
  for (int grp = 0; grp < 4; ++grp) {
    const int word0 = wslot * 128 + grp * 32;    // A: +0..15, B: +16..31

    for (int i = tid; i < 32 * 264 / 2; i += 512) ((unsigned*)&hbf[0][0])[i] = 0;
    for (int i = tid; i < 32 * TS; i += 512) sch[i] = chars[word0 * TS + i];

    float hA[2][4], hB[2][4];
    #pragma unroll
    for (int ct = 0; ct < 2; ++ct)
      #pragma unroll
      for (int r = 0; r < 4; ++r) { hA[ct][r] = 0.f; hB[ct][r] = 0.f; }

    __syncthreads();

    #pragma unroll 1
    for (int t = 0; t < TS; ++t) {
      const int ts = dir ? (TS - 1 - t) : t;

      // char codes only (LDS broadcast reads — no global-latency regs live
      // across the MFMA phase)
      int ccA[4], ccB[4];
      #pragma unroll
      for (int r = 0; r < 4; ++r) {
        ccA[r] = sch[(lr * 4 + r) * TS + ts];
        ccB[r] = sch[(16 + lr * 4 + r) * TS + ts];
      }

      // fused MFMA: one bh read serves both groups
      f4v azA[2], arA[2], ahA[2], azB[2], arB[2], ahB[2];
      #pragma unroll
      for (int ct = 0; ct < 2; ++ct) {
        azA[ct] = f4v{0.f, 0.f, 0.f, 0.f};
        arA[ct] = azA[ct];
        ahA[ct] = f4v{brh[ct], brh[ct], brh[ct], brh[ct]};
        azB[ct] = azA[ct];
        arB[ct] = azA[ct];
        ahB[ct] = ahA[ct];
      }
      #pragma unroll
      for (int kk = 0; kk < 8; ++kk) {
        const s8v aaA = __builtin_bit_cast(s8v, *(const uint4*)&hbf[lc][kk * 32 + lr * 8]);
        const s8v aaB = __builtin_bit_cast(s8v, *(const uint4*)&hbf[16 + lc][kk * 32 + lr * 8]);
        #pragma unroll
        for (int ct = 0; ct < 2; ++ct) {
          const s8v bz = __builtin_bit_cast(s8v, Wz[ct][kk]);
          const s8v br = __builtin_bit_cast(s8v, Wrr[ct][kk]);
          const s8v bh = __builtin_bit_cast(s8v, bhl[((w * 2 + ct) * 8 + kk) * 64 + lane]);
          azA[ct] = __builtin_amdgcn_mfma_f32_16x16x32_bf16(aaA, bz, azA[ct], 0, 0, 0);
          arA[ct] = __builtin_amdgcn_mfma_f32_16x16x32_bf16(aaA, br, arA[ct], 0, 0, 0);
          ahA[ct] = __builtin_amdgcn_mfma_f32_16x16x32_bf16(aaA, bh, ahA[ct], 0, 0, 0);
          azB[ct] = __builtin_amdgcn_mfma_f32_16x16x32_bf16(aaB, bz, azB[ct], 0, 0, 0);
          arB[ct] = __builtin_amdgcn_mfma_f32_16x16x32_bf16(aaB, br, arB[ct], 0, 0, 0);
          ahB[ct] = __builtin_amdgcn_mfma_f32_16x16x32_bf16(aaB, bh, ahB[ct], 0, 0, 0);
        }
      }
      __syncthreads();   // b1: all h-row reads complete

      // issue ALL gathers up front; latency hides under the other wave on
      // this SIMD + epi-A math
      float4 gA[2][4], gB[2][4];
      #pragma unroll
      for (int ct = 0; ct < 2; ++ct)
        #pragma unroll
        for (int r = 0; r < 4; ++r)
          gA[ct][r] = T4[ccA[r] * 256 + (ct ? u1 : u0)];
      #pragma unroll
      for (int ct = 0; ct < 2; ++ct)
        #pragma unroll
        for (int r = 0; r < 4; ++r)
          gB[ct][r] = T4[ccB[r] * 256 + (ct ? u1 : u0)];

      // epi-A (writes rows 0-15)
      #pragma unroll
      for (int ct = 0; ct < 2; ++ct)
        #pragma unroll
        for (int r = 0; r < 4; ++r) {
          const float4 g = gA[ct][r];
          const float z  = __builtin_amdgcn_rcpf(1.f + __builtin_amdgcn_exp2f(g.x + azA[ct][r]));
          const float rr = __builtin_amdgcn_rcpf(1.f + __builtin_amdgcn_exp2f(g.y + arA[ct][r]));
          const float hc = fmaf(-2.f, __builtin_amdgcn_rcpf(
              1.f + __builtin_amdgcn_exp2f(fmaf(rr, ahA[ct][r], g.z))), 1.f);
          const float hp = hA[ct][r];
          float hn = fmaf(1.f - z, hc - hp, hp);
          hn = (ccA[r] != 0) ? hn : hp;
          hA[ct][r] = hn;
          hbf[lr * 4 + r][ct ? u1 : u0] = bf16_rne(hn);
        }
      // epi-B (writes rows 16-31)
      #pragma unroll
      for (int ct = 0; ct < 2; ++ct)
        #pragma unroll
        for (int r = 0; r < 4; ++r) {
          const float4 g = gB[ct][r];
          const float z  = __builtin_amdgcn_rcpf(1.f + __builtin_amdgcn_exp2f(g.x + azB[ct][r]));
          const float rr = __builtin_amdgcn_rcpf(1.f + __builtin_amdgcn_exp2f(g.y + arB[ct][r]));
          const float hc = fmaf(-2.f, __builtin_amdgcn_rcpf(
              1.f + __builtin_amdgcn_exp2f(fmaf(rr, ahB[ct][r], g.z))), 1.f);
          const float hp = hB[ct][r];
          float hn = fmaf(1.f - z, hc - hp, hp);
          hn = (ccB[r] != 0) ? hn : hp;
          hB[ct][r] = hn;
          hbf[16 + lr * 4 + r][ct ? u1 : u0] = bf16_rne(hn);
        }
      __syncthreads();   // b2: writes complete before next step's reads
    }

    // store both groups' outputs from registers
    #pragma unroll
    for (int ct = 0; ct < 2; ++ct)
      #pragma unroll
      for (int r = 0; r < 4; ++r) {
        out[(size_t)(word0 + lr * 4 + r) * 512 + dir * 256 + (ct ? u1 : u0)] = hA[ct][r];
        out[(size_t)(word0 + 16 + lr * 4 + r) * 512 + dir * 256 + (ct ? u1 : u0)] = hB[ct][r];
      }
    __syncthreads();   // guard hbf/sch reuse vs next group's init
  }
}

extern "C" void kernel_launch(void* const* d_in, const int* in_sizes, int n_in,
                              void* d_out, int out_size, void* d_ws, size_t ws_size,
                              hipStream_t stream) {
  const int* chars = (const int*)d_in[0];
  const float* emb = (const float*)d_in[1];
  const float* wkF = (const float*)d_in[2];
  const float* wrF = (const float*)d_in[3];
  const float* bF  = (const float*)d_in[4];
  const float* wkB = (const float*)d_in[5];
  const float* wrB = (const float*)d_in[6];
  const float* bB  = (const float*)d_in[7];
  float* outp = (float*)d_out;

  float* tab4 = (float*)d_ws;                               // 2*129*256*16B = 1056768
  uint4* wrp  = (uint4*)((char*)d_ws + 1056768);            // 2*48*8*64*16B = 786432

  build_tab<<<(2 * 129 * 768 + 255) / 256, 256, 0, stream>>>(emb, wkF, bF, wkB, bB, tab4);
  pack_wr<<<(2 * 48 * 8 * 64 + 255) / 256, 256, 0, stream>>>(wrF, wrB, wrp);
  gru_main<<<NBLK, 512, 0, stream>>>(chars, tab4, wrp, bF, bB, outp);
}

// Round 13
// 289.382 us; speedup vs baseline: 1.2268x; 1.2268x over previous
//
#include <hip/hip_runtime.h>
#include <hip/hip_bf16.h>

#define TS 20
#define DNUM 128
#define NWORDS 16384
#define NBLK 256                    // 1 block/CU; bid>>7 = dir

typedef __attribute__((ext_vector_type(8))) short s8v;
typedef __attribute__((ext_vector_type(4))) float f4v;

#define L2E 1.4426950408889634f

__device__ __forceinline__ unsigned short bf16_rne(float f) {
  union { float f; unsigned u; } x; x.f = f;
  unsigned r = x.u + 0x7fffu + ((x.u >> 16) & 1u);
  return (unsigned short)(r >> 16);
}

// tab2[dir][c][u] = (-L2E*(xz + b_rec_z), -L2E*(xr + b_rec_r)); xg incl b_in.
// tabh[dir][c][u] = 2*L2E*xh.   (b_rec_h cannot fold: it sits inside r*(...))
__global__ void build_tab(const float* __restrict__ emb,
                          const float* __restrict__ wkF, const float* __restrict__ bF,
                          const float* __restrict__ wkB, const float* __restrict__ bB,
                          float* __restrict__ tab2, float* __restrict__ tabh) {
  int gid = blockIdx.x * 256 + threadIdx.x;
  if (gid >= 2 * 129 * 768) return;
  int dir = gid / (129 * 768);
  int rem = gid - dir * (129 * 768);
  int c = rem / 768, j = rem - (rem / 768) * 768;
  int g = j >> 8, u = j & 255;
  const float* Wk = dir ? wkB : wkF;
  const float* bb = dir ? bB : bF;
  float s = bb[j];                       // b[0] row = input bias
  const float* er = emb + c * DNUM;
  #pragma unroll 4
  for (int d = 0; d < DNUM; ++d) s = fmaf(er[d], Wk[d * 768 + j], s);
  if (g < 2) tab2[(((size_t)dir * 129 + c) * 256 + u) * 2 + g] = -L2E * (s + bb[768 + j]);
  else       tabh[((size_t)dir * 129 + c) * 256 + u] = 2.f * L2E * s;
}

// Pack Wr into bf16 MFMA-B-fragment order (verified r1), pre-scaled per gate.
__global__ void pack_wr(const float* __restrict__ wrF, const float* __restrict__ wrB,
                        uint4* __restrict__ wp) {
  int gid = blockIdx.x * 256 + threadIdx.x;
  if (gid >= 2 * 48 * 8 * 64) return;
  int dir = gid / (48 * 8 * 64);
  int rem = gid - dir * (48 * 8 * 64);
  int ct = rem / (8 * 64);
  int kk = (rem / 64) & 7;
  int lane = rem & 63;
  const float* Wr = dir ? wrB : wrF;
  int n = ct * 16 + (lane & 15);
  int k0 = kk * 32 + (lane >> 4) * 8;
  const float sc = (ct >> 4) == 2 ? (2.f * L2E) : (-L2E);
  union { unsigned short v[8]; uint4 q; } u;
  #pragma unroll
  for (int e = 0; e < 8; ++e) u.v[e] = bf16_rne(sc * Wr[(k0 + e) * 768 + n]);
  wp[gid] = u.q;
}

// r8 structure (champion, 322us, no spill) + DOUBLE-BUFFERED h state:
// step t reads hbf[t&1], writes hbf[(t+1)&1]; ONE barrier per step orders
// write(t) < read(t+1) and read(t) < write(t+1). Halves barrier drains.
// 256 blocks (1/CU) x 512 threads (8 waves, 2/SIMD). Wave = 32 units x 3
// gates, 16 words/step. z,r weights in 128 regs (AGPR-parked by compiler —
// B-operands tolerate this, r8 evidence); h-gate panel in 128KB LDS.
__global__ __launch_bounds__(512, 2) void gru_main(
    const int* __restrict__ chars, const float* __restrict__ tab2,
    const float* __restrict__ tabh, const uint4* __restrict__ wrp,
    const float* __restrict__ bf_, const float* __restrict__ bb_,
    float* __restrict__ out) {
  const int bid = blockIdx.x;
  const int dir = bid >> 7;            // 128 blocks per direction
  const int wslot = bid & 127;
  const float2* T2 = (const float2*)tab2 + (size_t)dir * 129 * 256;
  const float*  TH = tabh + (size_t)dir * 129 * 256;
  const uint4* WP = wrp + dir * (48 * 8 * 64);
  const float* brec = (dir ? bb_ : bf_) + 768;   // b[1] = recurrent bias

  const int tid = threadIdx.x;
  const int w = tid >> 6, lane = tid & 63;
  const int lr = lane >> 4, lc = lane & 15;
  const int u0 = w * 32 + lc, u1 = u0 + 16;      // wave's two unit-tiles

  __shared__ uint4 bhl[8192];                    // 128KB h-gate weights
  __shared__ unsigned short hbf[2][16][264];     // 16.5KB dbuf; 528B stride -> 2-way
  __shared__ int sch[16 * TS];                   // 1.28KB chars

  for (int i = tid; i < 8192; i += 512) bhl[i] = WP[16384 + i];

  // z,r weights resident: 2 ct x 8 kk x 2 gates = 32 uint4 = 128 regs.
  uint4 Wz[2][8], Wrr[2][8];
  #pragma unroll
  for (int ct = 0; ct < 2; ++ct)
    #pragma unroll
    for (int kk = 0; kk < 8; ++kk) {
      Wz[ct][kk]  = WP[((w * 2 + ct) * 8 + kk) * 64 + lane];
      Wrr[ct][kk] = WP[((16 + w * 2 + ct) * 8 + kk) * 64 + lane];
    }

  float brh[2];
  brh[0] = 2.f * L2E * brec[512 + u0];
  brh[1] = 2.f * L2E * brec[512 + u1];

  #pragma unroll 1
  for (int grp = 0; grp < 8; ++grp) {
    const int word0 = wslot * 128 + grp * 16;

    for (int i = tid; i < 16 * 264 / 2; i += 512)
      ((unsigned*)&hbf[0][0][0])[i] = 0;         // zero buf 0 only
    for (int i = tid; i < 16 * TS; i += 512) sch[i] = chars[word0 * TS + i];

    float h[2][4];
    #pragma unroll
    for (int ct = 0; ct < 2; ++ct)
      #pragma unroll
      for (int r = 0; r < 4; ++r) h[ct][r] = 0.f;

    __syncthreads();

    #pragma unroll 1
    for (int t = 0; t < TS; ++t) {
      const int ts = dir ? (TS - 1 - t) : t;
      const unsigned short (*rd)[264] = hbf[t & 1];
      unsigned short (*wr)[264] = hbf[(t + 1) & 1];

      // cc + z,r-logit prefetch (L2 latency hides under the MFMA phase)
      int cc[4];
      #pragma unroll
      for (int r = 0; r < 4; ++r) cc[r] = sch[(lr * 4 + r) * TS + ts];
      float2 p[2][4];
      #pragma unroll
      for (int ct = 0; ct < 2; ++ct)
        #pragma unroll
        for (int r = 0; r < 4; ++r)
          p[ct][r] = T2[cc[r] * 256 + (ct ? u1 : u0)];

      f4v az[2], ar[2], ah[2];
      #pragma unroll
      for (int ct = 0; ct < 2; ++ct) {
        az[ct] = f4v{0.f, 0.f, 0.f, 0.f};
        ar[ct] = az[ct];
        ah[ct] = f4v{brh[ct], brh[ct], brh[ct], brh[ct]};
      }
      #pragma unroll
      for (int kk = 0; kk < 8; ++kk) {
        const s8v aa = __builtin_bit_cast(s8v, *(const uint4*)&rd[lc][kk * 32 + lr * 8]);
        #pragma unroll
        for (int ct = 0; ct < 2; ++ct) {
          const uint4 bh = bhl[((w * 2 + ct) * 8 + kk) * 64 + lane];
          az[ct] = __builtin_amdgcn_mfma_f32_16x16x32_bf16(aa, __builtin_bit_cast(s8v, Wz[ct][kk]),  az[ct], 0, 0, 0);
          ar[ct] = __builtin_amdgcn_mfma_f32_16x16x32_bf16(aa, __builtin_bit_cast(s8v, Wrr[ct][kk]), ar[ct], 0, 0, 0);
          ah[ct] = __builtin_amdgcn_mfma_f32_16x16x32_bf16(aa, __builtin_bit_cast(s8v, bh),          ah[ct], 0, 0, 0);
        }
      }

      // epilogue: no barrier needed before it — MFMA reads rd, epi writes wr
      #pragma unroll
      for (int ct = 0; ct < 2; ++ct)
        #pragma unroll
        for (int r = 0; r < 4; ++r) {
          const float q = TH[cc[r] * 256 + (ct ? u1 : u0)];
          const float z  = __builtin_amdgcn_rcpf(1.f + __builtin_amdgcn_exp2f(p[ct][r].x + az[ct][r]));
          const float rr = __builtin_amdgcn_rcpf(1.f + __builtin_amdgcn_exp2f(p[ct][r].y + ar[ct][r]));
          const float hc = fmaf(-2.f, __builtin_amdgcn_rcpf(
              1.f + __builtin_amdgcn_exp2f(fmaf(rr, ah[ct][r], q))), 1.f);
          const float hp = h[ct][r];
          float hn = fmaf(1.f - z, hc - hp, hp);
          hn = (cc[r] != 0) ? hn : hp;
          h[ct][r] = hn;
          wr[lr * 4 + r][ct ? u1 : u0] = bf16_rne(hn);
        }
      __syncthreads();   // single barrier: wr complete before next step reads
    }

    // store this group's outputs
    #pragma unroll
    for (int ct = 0; ct < 2; ++ct)
      #pragma unroll
      for (int r = 0; r < 4; ++r)
        out[(size_t)(word0 + lr * 4 + r) * 512 + dir * 256 + (ct ? u1 : u0)] = h[ct][r];
    __syncthreads();   // guard hbf/sch reuse vs next group's init
  }
}

extern "C" void kernel_launch(void* const* d_in, const int* in_sizes, int n_in,
                              void* d_out, int out_size, void* d_ws, size_t ws_size,
                              hipStream_t stream) {
  const int* chars = (const int*)d_in[0];
  const float* emb = (const float*)d_in[1];
  const float* wkF = (const float*)d_in[2];
  const float* wrF = (const float*)d_in[3];
  const float* bF  = (const float*)d_in[4];
  const float* wkB = (const float*)d_in[5];
  const float* wrB = (const float*)d_in[6];
  const float* bB  = (const float*)d_in[7];
  float* outp = (float*)d_out;

  float* tab2 = (float*)d_ws;                                   // 2*129*256*8B  = 528384
  float* tabh = (float*)((char*)d_ws + 528384);                 // 2*129*256*4B  = 264192
  uint4* wrp  = (uint4*)((char*)d_ws + 528384 + 264192);        // 2*48*8*64*16B = 786432

  build_tab<<<(2 * 129 * 768 + 255) / 256, 256, 0, stream>>>(emb, wkF, bF, wkB, bB, tab2, tabh);
  pack_wr<<<(2 * 48 * 8 * 64 + 255) / 256, 256, 0, stream>>>(wrF, wrB, wrp);
  gru_main<<<NBLK, 512, 0, stream>>>(chars, tab2, tabh, wrp, bF, bB, outp);
}